// Round 4
// baseline (209.276 us; speedup 1.0000x reference)
//
#include <hip/hip_runtime.h>

#define NR 131072
#define DD 32
#define KK 64
#define BETA_C 10.0f

// ---------------------------------------------------------------------------
// ws layout (float-indexed):
//   [0,64)        fill_g   (float, atomic accum of softmax p sums)
//   [64,128)      counts_g (int)
//   [128,132)     lossAcc  (float scalar, atomic)
//   [192,2240)    sums_g   (float, K*D)
//   [2240,67776)  m2_g     (float, K*D*D; only lower triangle i>=j written)
//   [67776,100544) pred8   (uchar, N bytes)
// memset zeroes the first 67776 floats each launch (ws re-poisoned 0xAA).
// ---------------------------------------------------------------------------

// phase 1 v4: k-split. Each row is processed by a PAIR of waves (wave h=0:
// clusters 0..31, h=1: 32..63; wave-uniform half so centers stay on the
// s_load/K$ path). Halves merge via online-softmax through LDS. Grid = NR/128
// -> 16 waves/CU (2x R3). 32-value 5-stage transpose-reduce for the filling
// sum (same recursive-halving scheme as validated R3 64-value version).
__global__ __launch_bounds__(256) void phase1_kernel(
    const float* __restrict__ x, const float* __restrict__ centers,
    float* __restrict__ fill_g, unsigned char* __restrict__ pred_g) {
  __shared__ float cnS[KK];       // ||c_k||^2
  __shared__ float bestH[2][128];
  __shared__ float ssumH[2][128];
  __shared__ int biH[2][128];
  __shared__ float fillW[2][KK];  // [rowgroup][k]

  const int tid = threadIdx.x;
  const int lane = tid & 63;
  const int wav = tid >> 6;  // 0..3
  const int h = wav & 1;     // cluster half
  const int g = wav >> 1;    // row group
  const int hU = __builtin_amdgcn_readfirstlane(h);  // SGPR -> uniform loads
  const int rloc = g * 64 + lane;
  const int row = blockIdx.x * 128 + rloc;  // grid == NR/128 exactly

  if (tid < KK) {
    float s = 0.f;
    const float* cp = centers + tid * DD;
#pragma unroll
    for (int j = 0; j < DD; ++j) s += cp[j] * cp[j];
    cnS[tid] = s;
  }
  __syncthreads();

  float xr[DD];  // row in VGPRs, compile-time indexed
  const float4* xp = (const float4*)(x + (size_t)row * DD);
#pragma unroll
  for (int j = 0; j < 8; ++j) {
    const float4 v = xp[j];
    xr[4 * j + 0] = v.x;
    xr[4 * j + 1] = v.y;
    xr[4 * j + 2] = v.z;
    xr[4 * j + 3] = v.w;
  }
  float xx = 0.f;
#pragma unroll
  for (int j = 0; j < DD; ++j) xx += xr[j] * xr[j];

  const float* cb = centers + hU * 32 * DD;  // uniform base
  float pv[32];
  float best = 3.4e38f;
  int bi = 0;
#pragma unroll
  for (int kk = 0; kk < 32; ++kk) {
    float dot = 0.f;
#pragma unroll
    for (int j = 0; j < DD; ++j)
      dot += xr[j] * cb[kk * DD + j];  // uniform addr -> s_load (K$)
    const float d2 = xx - 2.0f * dot + cnS[hU * 32 + kk];
    pv[kk] = d2;
    if (d2 < best) { best = d2; bi = hU * 32 + kk; }  // first-index ties
  }

  // local softmax over my half (args <= 0, no overflow)
  float ssum = 0.f;
#pragma unroll
  for (int kk = 0; kk < 32; ++kk) {
    const float e = __expf(BETA_C * (best - pv[kk]));
    pv[kk] = e;
    ssum += e;
  }

  // cross-half online-softmax merge through LDS
  bestH[h][rloc] = best;
  ssumH[h][rloc] = ssum;
  biH[h][rloc] = bi;
  __syncthreads();
  const float bo = bestH[1 - h][rloc];
  const float so = ssumH[1 - h][rloc];
  const int bio = biH[1 - h][rloc];
  const float bm = fminf(best, bo);
  const float fs = __expf(BETA_C * (bm - best));
  const float fo = __expf(BETA_C * (bm - bo));
  const float scale = fs / (ssum * fs + so * fo);
  if (h == 0) {
    // equality -> keep half0's bi (lower k) == reference first-index argmin
    const int bim = (bo < best) ? bio : bi;
    pred_g[row] = (unsigned char)bim;
  }
#pragma unroll
  for (int kk = 0; kk < 32; ++kk) pv[kk] *= scale;

  // transpose-reduce: 32 values over 64 lanes (rows). Stages consume lane
  // bits 4..0; lane l ends holding sum over its bit5-half of p[kbase+(l&31)];
  // final xor-32 completes the 64-row sum.
#pragma unroll
  for (int m = 16; m >= 1; m >>= 1) {
    const bool hi_ = (lane & m) != 0;
#pragma unroll
    for (int i = 0; i < m; ++i) {
      const float send = hi_ ? pv[i] : pv[i + m];
      const float recv = __shfl_xor(send, m, 64);
      const float keep = hi_ ? pv[i + m] : pv[i];
      pv[i] = keep + recv;
    }
  }
  const float tot = pv[0] + __shfl_xor(pv[0], 32, 64);
  if (lane < 32) fillW[g][hU * 32 + lane] = tot;
  __syncthreads();
  if (tid < KK) atomicAdd(&fill_g[tid], fillW[0][tid] + fillW[1][tid]);
}

// phase 3 v3: gather-SYRK with fine chunks for load balance.
// CH=128 -> 8192 blocks, 1024 rows each (avg ~16 matches/block; worst-case
// cluster tail shrinks 4x vs CH=32). uchar pred scan: 1 uchar4 + 4 ballot
// rounds per thread.
#define CH 128
#define RPB (NR / CH)  // 1024 rows per block

__global__ __launch_bounds__(256) void phase3_kernel(
    const float* __restrict__ x, const unsigned char* __restrict__ pred_g,
    int* __restrict__ counts_g, float* __restrict__ sums_g,
    float* __restrict__ m2_g) {
  __shared__ unsigned short idxList[RPB];  // local row offsets (2 KB)
  __shared__ float xs[64 * DD];            // gathered row tile (8 KB)
  __shared__ int cntS;

  const int tid = threadIdx.x;
  const int lane = tid & 63;
  const int k = blockIdx.x & (KK - 1);
  const int chunk = blockIdx.x >> 6;
  const int base = chunk * RPB;

  if (tid == 0) cntS = 0;
  __syncthreads();

  // scan + wave-ballot compaction (1 LDS atomic per wave-round)
  const uchar4 p4 = *(const uchar4*)(pred_g + base + tid * 4);
  const int pr[4] = {p4.x, p4.y, p4.z, p4.w};
#pragma unroll
  for (int c = 0; c < 4; ++c) {
    const bool match = (pr[c] == k);
    const unsigned long long mask = __ballot(match);
    const int tot = __popcll(mask);
    const int pre = __builtin_amdgcn_mbcnt_hi(
        (unsigned)(mask >> 32), __builtin_amdgcn_mbcnt_lo((unsigned)mask, 0));
    int b = 0;
    if (lane == 0 && tot) b = atomicAdd(&cntS, tot);
    b = __shfl(b, 0, 64);
    if (match) idxList[b + pre] = (unsigned short)(tid * 4 + c);
  }
  __syncthreads();
  const int m = cntS;  // uniform

  const int ti = tid >> 4, tj = tid & 15;
  const int i0 = ti, i1 = ti + 16, j0 = tj, j1 = tj + 16;
  float c00 = 0.f, c10 = 0.f, c11 = 0.f;
  const int scol = tid & 31, srow0 = tid >> 5;
  float sd = 0.f;

  for (int off = 0; off < m; off += 64) {
    const int cnt = min(64, m - off);
    __syncthreads();  // previous tile's readers done before overwrite
    for (int e = tid; e < cnt * DD; e += 256) {
      const int r = base + (int)idxList[off + (e >> 5)];
      xs[e] = x[(size_t)r * DD + (e & 31)];  // 128B row segments
    }
    __syncthreads();
    for (int r = srow0; r < cnt; r += 8) sd += xs[r * DD + scol];
    int r = 0;
    for (; r + 4 <= cnt; r += 4) {
#pragma unroll
      for (int u = 0; u < 4; ++u) {
        const float* xrp = xs + (r + u) * DD;
        const float a0 = xrp[i0], a1 = xrp[i1];
        const float b0 = xrp[j0], b1 = xrp[j1];
        c00 += a0 * b0;
        c10 += a1 * b0;
        c11 += a1 * b1;
      }
    }
    for (; r < cnt; ++r) {
      const float* xrp = xs + r * DD;
      const float a0 = xrp[i0], a1 = xrp[i1];
      const float b0 = xrp[j0], b1 = xrp[j1];
      c00 += a0 * b0;
      c10 += a1 * b0;
      c11 += a1 * b1;
    }
  }

  if (m > 0) {
    float* m2k = m2_g + k * (DD * DD);
    atomicAdd(&m2k[i1 * DD + j0], c10);
    if (tj <= ti) {
      atomicAdd(&m2k[i0 * DD + j0], c00);
      atomicAdd(&m2k[i1 * DD + j1], c11);
    }
    atomicAdd(&sums_g[k * DD + scol], sd);
    if (tid == 0) atomicAdd(&counts_g[k], m);
  }
}

// finalize A: one block per cluster; all three loss terms -> atomic scalar.
__global__ __launch_bounds__(256) void finalizeA_kernel(
    const float* __restrict__ fill_g, const int* __restrict__ counts_g,
    const float* __restrict__ sums_g, const float* __restrict__ m2_g,
    const float* __restrict__ ft, const float* __restrict__ mt,
    const float* __restrict__ ct, float* __restrict__ lossAcc) {
  __shared__ float meanS[DD];
  __shared__ float wred[4];
  const int t = threadIdx.x;
  const int k = blockIdx.x;

  const float inv = 1.0f / fmaxf((float)counts_g[k], 1.0f);
  if (t < DD) meanS[t] = sums_g[k * DD + t] * inv;
  __syncthreads();

  float acc = 0.f;
  if (t < DD) {
    const float d = meanS[t] - mt[k * DD + t];
    acc += d * d * (1.0f / (KK * DD));
  }
  if (t == 0) {
    const float f = fill_g[k] * (1.0f / (float)NR) - ft[k];
    acc += f * f * (1.0f / KK);
  }
  const float* m2k = m2_g + k * (DD * DD);
  const float* ctk = ct + k * (DD * DD);
#pragma unroll
  for (int u = 0; u < 4; ++u) {
    const int e = t + 256 * u;  // coalesced ct reads
    const int i = e >> 5, j = e & 31;
    const float val = (i >= j) ? m2k[i * DD + j] : m2k[j * DD + i];  // mirror
    const float cov = val * inv - meanS[i] * meanS[j];
    const float d = cov - ctk[e];
    acc += d * d * (1.0f / (KK * DD * DD));
  }

  acc += __shfl_xor(acc, 32, 64);
  acc += __shfl_xor(acc, 16, 64);
  acc += __shfl_xor(acc, 8, 64);
  acc += __shfl_xor(acc, 4, 64);
  acc += __shfl_xor(acc, 2, 64);
  acc += __shfl_xor(acc, 1, 64);
  if ((t & 63) == 0) wred[t >> 6] = acc;
  __syncthreads();
  if (t == 0) atomicAdd(lossAcc, wred[0] + wred[1] + wred[2] + wred[3]);
}

// finalize B: copy the accumulated scalar to d_out.
__global__ void finalizeB_kernel(const float* __restrict__ lossAcc,
                                 float* __restrict__ out) {
  if (threadIdx.x == 0) out[0] = lossAcc[0];
}

extern "C" void kernel_launch(void* const* d_in, const int* in_sizes, int n_in,
                              void* d_out, int out_size, void* d_ws,
                              size_t ws_size, hipStream_t stream) {
  (void)in_sizes; (void)n_in; (void)out_size; (void)ws_size;
  const float* x = (const float*)d_in[0];
  const float* centers = (const float*)d_in[1];
  const float* ft = (const float*)d_in[2];
  const float* mt = (const float*)d_in[3];
  const float* ct = (const float*)d_in[4];
  float* out = (float*)d_out;

  float* ws = (float*)d_ws;
  float* fill_g = ws;                              // 64
  int* counts_g = (int*)(ws + 64);                 // 64
  float* lossAcc = ws + 128;                       // 1 (+pad)
  float* sums_g = ws + 192;                        // 2048
  float* m2_g = ws + 2240;                         // 65536 -> ends 67776
  unsigned char* pred8 = (unsigned char*)(ws + 67776);  // N bytes

  hipMemsetAsync(d_ws, 0, (size_t)67776 * sizeof(float), stream);

  phase1_kernel<<<NR / 128, 256, 0, stream>>>(x, centers, fill_g, pred8);
  phase3_kernel<<<KK * CH, 256, 0, stream>>>(x, pred8, counts_g, sums_g, m2_g);
  finalizeA_kernel<<<KK, 256, 0, stream>>>(fill_g, counts_g, sums_g, m2_g, ft,
                                           mt, ct, lossAcc);
  finalizeB_kernel<<<1, 64, 0, stream>>>(lossAcc, out);
}